// Round 1
// baseline (437.176 us; speedup 1.0000x reference)
//
#include <hip/hip_runtime.h>
#include <math.h>

#define T_ 4096
#define D_ 512
#define H_ 2048
#define E_ 16
#define RCAP 10240   // max padded rows: 8192 + 16*128

typedef short bf16x8 __attribute__((ext_vector_type(8)));
typedef float f32x4 __attribute__((ext_vector_type(4)));

__device__ __forceinline__ unsigned short f2bf(float f) {
  union { float f; unsigned u; } v; v.f = f;
  unsigned r = v.u + 0x7fffu + ((v.u >> 16) & 1u);
  return (unsigned short)(r >> 16);
}
__device__ __forceinline__ float bf2f(unsigned short u) {
  union { unsigned u; float f; } v; v.u = ((unsigned)u) << 16;
  return v.f;
}

// ---------------- K1: gate (one wave per token) ----------------
__global__ void gate_kernel(const float* __restrict__ x,
                            const float* __restrict__ Wg,
                            const float* __restrict__ bg,
                            float* __restrict__ out,
                            int* __restrict__ cnt,
                            int* __restrict__ tok2e) {
  const int lane = threadIdx.x & 63;
  const int t = blockIdx.x * 4 + (threadIdx.x >> 6);
  const int e = lane & 15, q = lane >> 4;
  const float4* x4 = (const float4*)(x + (size_t)t * D_ + q * 128);
  float acc = 0.f;
#pragma unroll 4
  for (int i = 0; i < 32; ++i) {
    float4 v = x4[i];
    const float* wp = Wg + (q * 128 + i * 4) * E_ + e;
    acc += v.x * wp[0];
    acc += v.y * wp[E_];
    acc += v.z * wp[2 * E_];
    acc += v.w * wp[3 * E_];
  }
  acc += __shfl_xor(acc, 16);
  acc += __shfl_xor(acc, 32);
  const float logit = acc + bg[e];
  // top-1
  float v1 = logit; int i1 = e;
#pragma unroll
  for (int s = 1; s < 16; s <<= 1) {
    float ov = __shfl_xor(v1, s); int oi = __shfl_xor(i1, s);
    if (ov > v1 || (ov == v1 && oi < i1)) { v1 = ov; i1 = oi; }
  }
  // top-2 (exclude argmax)
  float v2 = (e == i1) ? -INFINITY : logit; int i2 = e;
#pragma unroll
  for (int s = 1; s < 16; s <<= 1) {
    float ov = __shfl_xor(v2, s); int oi = __shfl_xor(i2, s);
    if (ov > v2 || (ov == v2 && oi < i2)) { v2 = ov; i2 = oi; }
  }
  if (lane == 0) {
    const float ed = __expf(v2 - v1);
    const float inv = 1.f / (1.f + ed);
    const size_t gidx = (size_t)T_ * D_;
    out[gidx + t * 2]     = (float)i1;          // gate_idx as float
    out[gidx + t * 2 + 1] = (float)i2;
    out[gidx + T_ * 2 + t * 2]     = inv;       // gate_score (softmax of 2)
    out[gidx + T_ * 2 + t * 2 + 1] = ed * inv;
    tok2e[t * 2] = i1; tok2e[t * 2 + 1] = i2;
    atomicAdd(&cnt[i1], 1); atomicAdd(&cnt[i2], 1);
  }
}

// ---------------- K2: offsets (pad each expert to 128 rows) ----------------
__global__ void setup_kernel(const int* __restrict__ cnt, int* __restrict__ cnt2,
                             int* __restrict__ offs, int* __restrict__ tileoff,
                             int* __restrict__ rowbuf) {
  if (threadIdx.x == 0) {
    int o = 0, to = 0;
    offs[0] = 0; tileoff[0] = 0;
    for (int e = 0; e < E_; ++e) {
      int mt = (cnt[e] + 127) >> 7;
      o += mt << 7; to += mt;
      offs[e + 1] = o; tileoff[e + 1] = to;
      cnt2[e] = 0;
    }
  }
  for (int i = threadIdx.x; i < RCAP; i += blockDim.x) rowbuf[i] = -1;
}

// ---------------- K3a: scatter token ids into expert row ranges ----------------
__global__ void scatter_kernel(const int* __restrict__ tok2e, int* __restrict__ cnt2,
                               const int* __restrict__ offs, int* __restrict__ rowbuf,
                               int* __restrict__ tok2row) {
  const int t = blockIdx.x * blockDim.x + threadIdx.x;
#pragma unroll
  for (int k = 0; k < 2; ++k) {
    int e = tok2e[t * 2 + k];
    int slot = atomicAdd(&cnt2[e], 1);
    int row = offs[e] + slot;
    rowbuf[row] = t;
    tok2row[t * 2 + k] = row;
  }
}

// ---------------- K3b: gather x rows -> compact bf16 xg ----------------
__global__ void gather_kernel(const float* __restrict__ x,
                              const int* __restrict__ rowbuf,
                              const int* __restrict__ offs,
                              unsigned short* __restrict__ xg) {
  const int row = blockIdx.x;
  if (row >= offs[16]) return;
  const int t = rowbuf[row];
  const int lane = threadIdx.x;  // 64 threads, 8 floats each
  float4 a = make_float4(0.f, 0.f, 0.f, 0.f), b = a;
  if (t >= 0) {
    const float4* p = (const float4*)(x + (size_t)t * D_ + lane * 8);
    a = p[0]; b = p[1];
  }
  unsigned w0 = f2bf(a.x) | (f2bf(a.y) << 16);
  unsigned w1 = f2bf(a.z) | (f2bf(a.w) << 16);
  unsigned w2 = f2bf(b.x) | (f2bf(b.y) << 16);
  unsigned w3 = f2bf(b.z) | (f2bf(b.w) << 16);
  *(uint4*)(xg + (size_t)row * D_ + lane * 8) = make_uint4(w0, w1, w2, w3);
}

// ---------------- K4/K5: tiled bf16 MFMA GEMM over expert row ranges ----------
// C[row0..row0+127][n0..n0+127] = act(A[rows][K] * B_e[K][NTOT] + bias_e)
// A: compact bf16 rows (stride KDIM). B: fp32 per-expert [KDIM][NTOT], transposed
// into LDS as bf16 at staging. Output: bf16, stride NTOT.
template <int KDIM, int NTOT, bool GELU>
__global__ __launch_bounds__(256) void ffn_gemm(
    const unsigned short* __restrict__ A_g, const float* __restrict__ B_g,
    const float* __restrict__ bias_g, unsigned short* __restrict__ out_g,
    const int* __restrict__ offs, const int* __restrict__ tileoff) {
  __shared__ unsigned short As[128][72];  // +8 bf16 pad -> 2-way banks (free)
  __shared__ unsigned short Bs[128][72];  // stored transposed: Bs[n][k]
  const int mt = blockIdx.x;
  if (mt >= tileoff[16]) return;
  int e = 0;
  while (tileoff[e + 1] <= mt) ++e;
  const int row0 = offs[e] + ((mt - tileoff[e]) << 7);
  const int n0 = blockIdx.y << 7;
  const int tid = threadIdx.x;
  const int lane = tid & 63;
  const int m_off = ((tid >> 6) & 1) << 6;   // wave -> 64x64 quadrant
  const int n_off = (tid >> 7) << 6;

  f32x4 zero = {0.f, 0.f, 0.f, 0.f};
  f32x4 acc[4][4];
#pragma unroll
  for (int i = 0; i < 4; ++i)
#pragma unroll
    for (int j = 0; j < 4; ++j) acc[i][j] = zero;

  const int arow = tid >> 1, ahalf = tid & 1;
  const unsigned short* Aptr = A_g + (size_t)(row0 + arow) * KDIM + ahalf * 32;
  const int bn = tid & 127, bkq = tid >> 7;  // 128 n-columns x 2 k-halves
  const float* Bptr = B_g + (size_t)e * KDIM * NTOT + (size_t)(bkq * 32) * NTOT + n0 + bn;

  for (int k0 = 0; k0 < KDIM; k0 += 64) {
    // stage A: 128 rows x 64 bf16 (each thread: 32 contiguous bf16)
    const uint4* asrc = (const uint4*)(Aptr + k0);
    uint4 a0 = asrc[0], a1 = asrc[1], a2 = asrc[2], a3 = asrc[3];
    // stage B transposed: thread owns one n-column, 32 k's (coalesced across lanes)
    const float* bsrc = Bptr + (size_t)k0 * NTOT;
    unsigned w[16];
#pragma unroll
    for (int kk = 0; kk < 16; ++kk) {
      unsigned lo = f2bf(bsrc[(size_t)(2 * kk) * NTOT]);
      unsigned hi = f2bf(bsrc[(size_t)(2 * kk + 1) * NTOT]);
      w[kk] = lo | (hi << 16);
    }
    uint4* adst = (uint4*)&As[arow][ahalf * 32];
    adst[0] = a0; adst[1] = a1; adst[2] = a2; adst[3] = a3;
    uint4* bdst = (uint4*)&Bs[bn][bkq * 32];
    bdst[0] = make_uint4(w[0], w[1], w[2], w[3]);
    bdst[1] = make_uint4(w[4], w[5], w[6], w[7]);
    bdst[2] = make_uint4(w[8], w[9], w[10], w[11]);
    bdst[3] = make_uint4(w[12], w[13], w[14], w[15]);
    __syncthreads();
#pragma unroll
    for (int kk = 0; kk < 64; kk += 32) {
      const int kidx = kk + ((lane >> 4) << 3);  // A[m][k=quad*8+j], B[k][n] sym.
      bf16x8 af[4], bfr[4];
#pragma unroll
      for (int i = 0; i < 4; ++i)
        af[i] = *(const bf16x8*)&As[m_off + i * 16 + (lane & 15)][kidx];
#pragma unroll
      for (int j = 0; j < 4; ++j)
        bfr[j] = *(const bf16x8*)&Bs[n_off + j * 16 + (lane & 15)][kidx];
#pragma unroll
      for (int i = 0; i < 4; ++i)
#pragma unroll
        for (int j = 0; j < 4; ++j)
          acc[i][j] = __builtin_amdgcn_mfma_f32_16x16x32_bf16(af[i], bfr[j], acc[i][j], 0, 0, 0);
    }
    __syncthreads();
  }
  // epilogue: C/D layout col=lane&15, row=quad*4+reg  (m89-verified)
  const float* bias = bias_g + (size_t)e * NTOT;
  const int quad = lane >> 4, lcol = lane & 15;
#pragma unroll
  for (int j = 0; j < 4; ++j) {
    const int col = n0 + n_off + j * 16 + lcol;
    const float bv = bias[col];
#pragma unroll
    for (int i = 0; i < 4; ++i) {
      const int rbase = row0 + m_off + i * 16 + (quad << 2);
      f32x4 v = acc[i][j];
#pragma unroll
      for (int r = 0; r < 4; ++r) {
        float y = v[r] + bv;
        if (GELU) y = 0.5f * y * (1.f + erff(y * 0.70710678118f));
        out_g[(size_t)(rbase + r) * NTOT + col] = f2bf(y);
      }
    }
  }
}

// ---------------- K6: combine the two expert rows per token ----------------
__global__ void combine_kernel(const unsigned short* __restrict__ ybuf,
                               const int* __restrict__ tok2row,
                               float* __restrict__ out) {
  const int t = blockIdx.x, lane = threadIdx.x;  // 64 threads x 8 floats
  const int rA = tok2row[t * 2], rB = tok2row[t * 2 + 1];
  const uint4 va = *(const uint4*)(ybuf + (size_t)rA * D_ + lane * 8);
  const uint4 vb = *(const uint4*)(ybuf + (size_t)rB * D_ + lane * 8);
  const unsigned short* pa = (const unsigned short*)&va;
  const unsigned short* pb = (const unsigned short*)&vb;
  float o[8];
#pragma unroll
  for (int i = 0; i < 8; ++i) o[i] = bf2f(pa[i]) + bf2f(pb[i]);
  float4* po = (float4*)(out + (size_t)t * D_ + lane * 8);
  po[0] = make_float4(o[0], o[1], o[2], o[3]);
  po[1] = make_float4(o[4], o[5], o[6], o[7]);
}

extern "C" void kernel_launch(void* const* d_in, const int* in_sizes, int n_in,
                              void* d_out, int out_size, void* d_ws, size_t ws_size,
                              hipStream_t stream) {
  const float* x  = (const float*)d_in[0];
  const float* Wg = (const float*)d_in[1];
  const float* bg = (const float*)d_in[2];
  const float* W1 = (const float*)d_in[3];
  const float* b1 = (const float*)d_in[4];
  const float* W2 = (const float*)d_in[5];
  const float* b2 = (const float*)d_in[6];
  float* out = (float*)d_out;
  char* ws = (char*)d_ws;

  // ws layout (needs ~52 MB):
  int* cnt     = (int*)(ws);            // 64 B (memset to 0)
  int* cnt2    = (int*)(ws + 256);      // 64 B
  int* offs    = (int*)(ws + 512);      // 17 ints
  int* tileoff = (int*)(ws + 1024);     // 17 ints
  int* tok2e   = (int*)(ws + 4096);     // 8192 ints
  int* tok2row = (int*)(ws + 4096 + 32768);   // 8192 ints
  int* rowbuf  = (int*)(ws + 4096 + 65536);   // RCAP ints, ends < 1 MB
  unsigned short* xg   = (unsigned short*)(ws + (1 << 20));   // RCAP*512 bf16 (10 MB)
  unsigned short* ybuf = xg;                                  // reuse: xg dead after GEMM1
  unsigned short* hbuf = (unsigned short*)(ws + (12 << 20));  // RCAP*2048 bf16 (40 MB)

  hipMemsetAsync(cnt, 0, 64, stream);
  gate_kernel<<<T_ / 4, 256, 0, stream>>>(x, Wg, bg, out, cnt, tok2e);
  setup_kernel<<<1, 256, 0, stream>>>(cnt, cnt2, offs, tileoff, rowbuf);
  scatter_kernel<<<T_ / 256, 256, 0, stream>>>(tok2e, cnt2, offs, rowbuf, tok2row);
  gather_kernel<<<RCAP, 64, 0, stream>>>(x, rowbuf, offs, xg);
  // GEMM1: h = gelu(xg @ W1 + b1)  -> hbuf   (K=512, N=2048)
  ffn_gemm<512, 2048, true><<<dim3(80, 16), 256, 0, stream>>>(xg, W1, b1, hbuf, offs, tileoff);
  // GEMM2: y = hbuf @ W2 + b2 -> ybuf        (K=2048, N=512)
  ffn_gemm<2048, 512, false><<<dim3(80, 4), 256, 0, stream>>>(hbuf, W2, b2, ybuf, offs, tileoff);
  combine_kernel<<<T_, 64, 0, stream>>>(ybuf, tok2row, out);
}

// Round 2
// 341.663 us; speedup vs baseline: 1.2796x; 1.2796x over previous
//
#include <hip/hip_runtime.h>
#include <math.h>

#define T_ 4096
#define D_ 512
#define H_ 2048
#define E_ 16
#define RCAP 10240   // max padded rows: 8192 + 16*128

typedef short bf16x8 __attribute__((ext_vector_type(8)));
typedef float f32x4 __attribute__((ext_vector_type(4)));

__device__ __forceinline__ unsigned short f2bf(float f) {
  union { float f; unsigned u; } v; v.f = f;
  unsigned r = v.u + 0x7fffu + ((v.u >> 16) & 1u);
  return (unsigned short)(r >> 16);
}
__device__ __forceinline__ float bf2f(unsigned short u) {
  union { unsigned u; float f; } v; v.u = ((unsigned)u) << 16;
  return v.f;
}

// ---------------- K1: gate (one wave per token) — NO atomics ----------------
__global__ void gate_kernel(const float* __restrict__ x,
                            const float* __restrict__ Wg,
                            const float* __restrict__ bg,
                            float* __restrict__ out,
                            int* __restrict__ tok2e) {
  const int lane = threadIdx.x & 63;
  const int t = blockIdx.x * 4 + (threadIdx.x >> 6);
  const int e = lane & 15, q = lane >> 4;
  const float4* x4 = (const float4*)(x + (size_t)t * D_ + q * 128);
  float acc = 0.f;
#pragma unroll 4
  for (int i = 0; i < 32; ++i) {
    float4 v = x4[i];
    const float* wp = Wg + (q * 128 + i * 4) * E_ + e;
    acc += v.x * wp[0];
    acc += v.y * wp[E_];
    acc += v.z * wp[2 * E_];
    acc += v.w * wp[3 * E_];
  }
  acc += __shfl_xor(acc, 16);
  acc += __shfl_xor(acc, 32);
  const float logit = acc + bg[e];
  // top-1
  float v1 = logit; int i1 = e;
#pragma unroll
  for (int s = 1; s < 16; s <<= 1) {
    float ov = __shfl_xor(v1, s); int oi = __shfl_xor(i1, s);
    if (ov > v1 || (ov == v1 && oi < i1)) { v1 = ov; i1 = oi; }
  }
  // top-2 (exclude argmax)
  float v2 = (e == i1) ? -INFINITY : logit; int i2 = e;
#pragma unroll
  for (int s = 1; s < 16; s <<= 1) {
    float ov = __shfl_xor(v2, s); int oi = __shfl_xor(i2, s);
    if (ov > v2 || (ov == v2 && oi < i2)) { v2 = ov; i2 = oi; }
  }
  if (lane == 0) {
    const float ed = __expf(v2 - v1);
    const float inv = 1.f / (1.f + ed);
    const size_t gidx = (size_t)T_ * D_;
    out[gidx + t * 2]     = (float)i1;          // gate_idx as float
    out[gidx + t * 2 + 1] = (float)i2;
    out[gidx + T_ * 2 + t * 2]     = inv;       // gate_score (softmax of 2)
    out[gidx + T_ * 2 + t * 2 + 1] = ed * inv;
    tok2e[t * 2] = i1; tok2e[t * 2 + 1] = i2;
  }
}

// ------- K2: histogram + offsets (LDS atomics; one block) + buffer init -------
__global__ void count_kernel(const int* __restrict__ tok2e,
                             int* __restrict__ cnt2,
                             int* __restrict__ offs, int* __restrict__ tileoff,
                             int* __restrict__ rowbuf) {
  __shared__ int h[E_];
  if (threadIdx.x < E_) h[threadIdx.x] = 0;
  __syncthreads();
  for (int i = threadIdx.x; i < 2 * T_; i += 256) atomicAdd(&h[tok2e[i]], 1);
  __syncthreads();
  if (threadIdx.x == 0) {
    int o = 0, to = 0;
    offs[0] = 0; tileoff[0] = 0;
    for (int e = 0; e < E_; ++e) {
      int mt = (h[e] + 127) >> 7;
      o += mt << 7; to += mt;
      offs[e + 1] = o; tileoff[e + 1] = to;
    }
  }
  // cnt2 padded: one cacheline (16 ints) per expert
  for (int i = threadIdx.x; i < E_ * 16; i += 256) cnt2[i] = 0;
  for (int i = threadIdx.x; i < RCAP; i += 256) rowbuf[i] = -1;
}

// ---------------- K3a: scatter token ids into expert row ranges ----------------
// cnt2 stride 16 -> per-expert atomic chains live on separate cachelines.
__global__ void scatter_kernel(const int* __restrict__ tok2e, int* __restrict__ cnt2,
                               const int* __restrict__ offs, int* __restrict__ rowbuf,
                               int* __restrict__ tok2row) {
  const int t = blockIdx.x * blockDim.x + threadIdx.x;
#pragma unroll
  for (int k = 0; k < 2; ++k) {
    int e = tok2e[t * 2 + k];
    int slot = atomicAdd(&cnt2[e * 16], 1);
    int row = offs[e] + slot;
    rowbuf[row] = t;
    tok2row[t * 2 + k] = row;
  }
}

// ---------------- K3b: gather x rows -> compact bf16 xg ----------------
__global__ void gather_kernel(const float* __restrict__ x,
                              const int* __restrict__ rowbuf,
                              const int* __restrict__ offs,
                              unsigned short* __restrict__ xg) {
  const int row = blockIdx.x;
  if (row >= offs[16]) return;
  const int t = rowbuf[row];
  const int lane = threadIdx.x;  // 64 threads, 8 floats each
  float4 a = make_float4(0.f, 0.f, 0.f, 0.f), b = a;
  if (t >= 0) {
    const float4* p = (const float4*)(x + (size_t)t * D_ + lane * 8);
    a = p[0]; b = p[1];
  }
  unsigned w0 = f2bf(a.x) | (f2bf(a.y) << 16);
  unsigned w1 = f2bf(a.z) | (f2bf(a.w) << 16);
  unsigned w2 = f2bf(b.x) | (f2bf(b.y) << 16);
  unsigned w3 = f2bf(b.z) | (f2bf(b.w) << 16);
  *(uint4*)(xg + (size_t)row * D_ + lane * 8) = make_uint4(w0, w1, w2, w3);
}

// ---------------- K4/K5: tiled bf16 MFMA GEMM over expert row ranges ----------
template <int KDIM, int NTOT, bool GELU>
__global__ __launch_bounds__(256) void ffn_gemm(
    const unsigned short* __restrict__ A_g, const float* __restrict__ B_g,
    const float* __restrict__ bias_g, unsigned short* __restrict__ out_g,
    const int* __restrict__ offs, const int* __restrict__ tileoff) {
  __shared__ unsigned short As[128][72];  // +8 bf16 pad -> 2-way banks (free)
  __shared__ unsigned short Bs[128][72];  // stored transposed: Bs[n][k]
  const int mt = blockIdx.x;
  if (mt >= tileoff[16]) return;
  int e = 0;
  while (tileoff[e + 1] <= mt) ++e;
  const int row0 = offs[e] + ((mt - tileoff[e]) << 7);
  const int n0 = blockIdx.y << 7;
  const int tid = threadIdx.x;
  const int lane = tid & 63;
  const int m_off = ((tid >> 6) & 1) << 6;   // wave -> 64x64 quadrant
  const int n_off = (tid >> 7) << 6;

  f32x4 zero = {0.f, 0.f, 0.f, 0.f};
  f32x4 acc[4][4];
#pragma unroll
  for (int i = 0; i < 4; ++i)
#pragma unroll
    for (int j = 0; j < 4; ++j) acc[i][j] = zero;

  const int arow = tid >> 1, ahalf = tid & 1;
  const unsigned short* Aptr = A_g + (size_t)(row0 + arow) * KDIM + ahalf * 32;
  const int bn = tid & 127, bkq = tid >> 7;  // 128 n-columns x 2 k-halves
  const float* Bptr = B_g + (size_t)e * KDIM * NTOT + (size_t)(bkq * 32) * NTOT + n0 + bn;

  for (int k0 = 0; k0 < KDIM; k0 += 64) {
    // stage A: 128 rows x 64 bf16 (each thread: 32 contiguous bf16)
    const uint4* asrc = (const uint4*)(Aptr + k0);
    uint4 a0 = asrc[0], a1 = asrc[1], a2 = asrc[2], a3 = asrc[3];
    // stage B transposed: thread owns one n-column, 32 k's (coalesced across lanes)
    const float* bsrc = Bptr + (size_t)k0 * NTOT;
    unsigned w[16];
#pragma unroll
    for (int kk = 0; kk < 16; ++kk) {
      unsigned lo = f2bf(bsrc[(size_t)(2 * kk) * NTOT]);
      unsigned hi = f2bf(bsrc[(size_t)(2 * kk + 1) * NTOT]);
      w[kk] = lo | (hi << 16);
    }
    uint4* adst = (uint4*)&As[arow][ahalf * 32];
    adst[0] = a0; adst[1] = a1; adst[2] = a2; adst[3] = a3;
    uint4* bdst = (uint4*)&Bs[bn][bkq * 32];
    bdst[0] = make_uint4(w[0], w[1], w[2], w[3]);
    bdst[1] = make_uint4(w[4], w[5], w[6], w[7]);
    bdst[2] = make_uint4(w[8], w[9], w[10], w[11]);
    bdst[3] = make_uint4(w[12], w[13], w[14], w[15]);
    __syncthreads();
#pragma unroll
    for (int kk = 0; kk < 64; kk += 32) {
      const int kidx = kk + ((lane >> 4) << 3);
      bf16x8 af[4], bfr[4];
#pragma unroll
      for (int i = 0; i < 4; ++i)
        af[i] = *(const bf16x8*)&As[m_off + i * 16 + (lane & 15)][kidx];
#pragma unroll
      for (int j = 0; j < 4; ++j)
        bfr[j] = *(const bf16x8*)&Bs[n_off + j * 16 + (lane & 15)][kidx];
#pragma unroll
      for (int i = 0; i < 4; ++i)
#pragma unroll
        for (int j = 0; j < 4; ++j)
          acc[i][j] = __builtin_amdgcn_mfma_f32_16x16x32_bf16(af[i], bfr[j], acc[i][j], 0, 0, 0);
    }
    __syncthreads();
  }
  // epilogue: C/D layout col=lane&15, row=quad*4+reg  (m89-verified)
  const float* bias = bias_g + (size_t)e * NTOT;
  const int quad = lane >> 4, lcol = lane & 15;
#pragma unroll
  for (int j = 0; j < 4; ++j) {
    const int col = n0 + n_off + j * 16 + lcol;
    const float bv = bias[col];
#pragma unroll
    for (int i = 0; i < 4; ++i) {
      const int rbase = row0 + m_off + i * 16 + (quad << 2);
      f32x4 v = acc[i][j];
#pragma unroll
      for (int r = 0; r < 4; ++r) {
        float y = v[r] + bv;
        if (GELU) y = 0.5f * y * (1.f + erff(y * 0.70710678118f));
        out_g[(size_t)(rbase + r) * NTOT + col] = f2bf(y);
      }
    }
  }
}

// ---------------- K6: combine the two expert rows per token ----------------
__global__ void combine_kernel(const unsigned short* __restrict__ ybuf,
                               const int* __restrict__ tok2row,
                               float* __restrict__ out) {
  const int t = blockIdx.x, lane = threadIdx.x;  // 64 threads x 8 floats
  const int rA = tok2row[t * 2], rB = tok2row[t * 2 + 1];
  const uint4 va = *(const uint4*)(ybuf + (size_t)rA * D_ + lane * 8);
  const uint4 vb = *(const uint4*)(ybuf + (size_t)rB * D_ + lane * 8);
  const unsigned short* pa = (const unsigned short*)&va;
  const unsigned short* pb = (const unsigned short*)&vb;
  float o[8];
#pragma unroll
  for (int i = 0; i < 8; ++i) o[i] = bf2f(pa[i]) + bf2f(pb[i]);
  float4* po = (float4*)(out + (size_t)t * D_ + lane * 8);
  po[0] = make_float4(o[0], o[1], o[2], o[3]);
  po[1] = make_float4(o[4], o[5], o[6], o[7]);
}

extern "C" void kernel_launch(void* const* d_in, const int* in_sizes, int n_in,
                              void* d_out, int out_size, void* d_ws, size_t ws_size,
                              hipStream_t stream) {
  const float* x  = (const float*)d_in[0];
  const float* Wg = (const float*)d_in[1];
  const float* bg = (const float*)d_in[2];
  const float* W1 = (const float*)d_in[3];
  const float* b1 = (const float*)d_in[4];
  const float* W2 = (const float*)d_in[5];
  const float* b2 = (const float*)d_in[6];
  float* out = (float*)d_out;
  char* ws = (char*)d_ws;

  // ws layout (needs ~52 MB):
  int* cnt2    = (int*)(ws);            // 16 experts x 16-int stride (1 KB)
  int* offs    = (int*)(ws + 2048);     // 17 ints
  int* tileoff = (int*)(ws + 3072);     // 17 ints
  int* tok2e   = (int*)(ws + 4096);     // 8192 ints
  int* tok2row = (int*)(ws + 4096 + 32768);   // 8192 ints
  int* rowbuf  = (int*)(ws + 4096 + 65536);   // RCAP ints, ends < 1 MB
  unsigned short* xg   = (unsigned short*)(ws + (1 << 20));   // RCAP*512 bf16 (10 MB)
  unsigned short* ybuf = xg;                                  // reuse: xg dead after GEMM1
  unsigned short* hbuf = (unsigned short*)(ws + (12 << 20));  // RCAP*2048 bf16 (40 MB)

  gate_kernel<<<T_ / 4, 256, 0, stream>>>(x, Wg, bg, out, tok2e);
  count_kernel<<<1, 256, 0, stream>>>(tok2e, cnt2, offs, tileoff, rowbuf);
  scatter_kernel<<<T_ / 256, 256, 0, stream>>>(tok2e, cnt2, offs, rowbuf, tok2row);
  gather_kernel<<<RCAP, 64, 0, stream>>>(x, rowbuf, offs, xg);
  // GEMM1: h = gelu(xg @ W1 + b1)  -> hbuf   (K=512, N=2048)
  ffn_gemm<512, 2048, true><<<dim3(80, 16), 256, 0, stream>>>(xg, W1, b1, hbuf, offs, tileoff);
  // GEMM2: y = hbuf @ W2 + b2 -> ybuf        (K=2048, N=512)
  ffn_gemm<2048, 512, false><<<dim3(80, 4), 256, 0, stream>>>(hbuf, W2, b2, ybuf, offs, tileoff);
  combine_kernel<<<T_, 64, 0, stream>>>(ybuf, tok2row, out);
}

// Round 4
// 315.542 us; speedup vs baseline: 1.3855x; 1.0828x over previous
//
#include <hip/hip_runtime.h>
#include <math.h>

#define T_ 4096
#define D_ 512
#define H_ 2048
#define E_ 16
#define RCAP 10240   // max padded rows: 8192 + 16*128

typedef short bf16x8 __attribute__((ext_vector_type(8)));
typedef float f32x4 __attribute__((ext_vector_type(4)));

__device__ __forceinline__ unsigned short f2bf(float f) {
  union { float f; unsigned u; } v; v.f = f;
  unsigned r = v.u + 0x7fffu + ((v.u >> 16) & 1u);
  return (unsigned short)(r >> 16);
}
__device__ __forceinline__ float bf2f(unsigned short u) {
  union { unsigned u; float f; } v; v.u = ((unsigned)u) << 16;
  return v.f;
}

// ---------------- K1: gate (one wave per token) — NO atomics ----------------
__global__ void gate_kernel(const float* __restrict__ x,
                            const float* __restrict__ Wg,
                            const float* __restrict__ bg,
                            float* __restrict__ out,
                            int* __restrict__ tok2e) {
  const int lane = threadIdx.x & 63;
  const int t = blockIdx.x * 4 + (threadIdx.x >> 6);
  const int e = lane & 15, q = lane >> 4;
  const float4* x4 = (const float4*)(x + (size_t)t * D_ + q * 128);
  float acc = 0.f;
#pragma unroll 4
  for (int i = 0; i < 32; ++i) {
    float4 v = x4[i];
    const float* wp = Wg + (q * 128 + i * 4) * E_ + e;
    acc += v.x * wp[0];
    acc += v.y * wp[E_];
    acc += v.z * wp[2 * E_];
    acc += v.w * wp[3 * E_];
  }
  acc += __shfl_xor(acc, 16);
  acc += __shfl_xor(acc, 32);
  const float logit = acc + bg[e];
  float v1 = logit; int i1 = e;
#pragma unroll
  for (int s = 1; s < 16; s <<= 1) {
    float ov = __shfl_xor(v1, s); int oi = __shfl_xor(i1, s);
    if (ov > v1 || (ov == v1 && oi < i1)) { v1 = ov; i1 = oi; }
  }
  float v2 = (e == i1) ? -INFINITY : logit; int i2 = e;
#pragma unroll
  for (int s = 1; s < 16; s <<= 1) {
    float ov = __shfl_xor(v2, s); int oi = __shfl_xor(i2, s);
    if (ov > v2 || (ov == v2 && oi < i2)) { v2 = ov; i2 = oi; }
  }
  if (lane == 0) {
    const float ed = __expf(v2 - v1);
    const float inv = 1.f / (1.f + ed);
    const size_t gidx = (size_t)T_ * D_;
    out[gidx + t * 2]     = (float)i1;
    out[gidx + t * 2 + 1] = (float)i2;
    out[gidx + T_ * 2 + t * 2]     = inv;
    out[gidx + T_ * 2 + t * 2 + 1] = ed * inv;
    tok2e[t * 2] = i1; tok2e[t * 2 + 1] = i2;
  }
}

// ------- K2: histogram + offsets (LDS atomics; one block) + buffer init -------
__global__ void count_kernel(const int* __restrict__ tok2e,
                             int* __restrict__ cnt2,
                             int* __restrict__ offs, int* __restrict__ tileoff,
                             int* __restrict__ rowbuf) {
  __shared__ int h[E_];
  if (threadIdx.x < E_) h[threadIdx.x] = 0;
  __syncthreads();
  for (int i = threadIdx.x; i < 2 * T_; i += 256) atomicAdd(&h[tok2e[i]], 1);
  __syncthreads();
  if (threadIdx.x == 0) {
    int o = 0, to = 0;
    offs[0] = 0; tileoff[0] = 0;
    for (int e = 0; e < E_; ++e) {
      int mt = (h[e] + 127) >> 7;
      o += mt << 7; to += mt;
      offs[e + 1] = o; tileoff[e + 1] = to;
    }
  }
  for (int i = threadIdx.x; i < E_ * 16; i += 256) cnt2[i] = 0;
  for (int i = threadIdx.x; i < RCAP; i += 256) rowbuf[i] = -1;
}

// ---------------- K3a: scatter (cnt2 padded to one line/expert) ----------------
__global__ void scatter_kernel(const int* __restrict__ tok2e, int* __restrict__ cnt2,
                               const int* __restrict__ offs, int* __restrict__ rowbuf,
                               int* __restrict__ tok2row) {
  const int t = blockIdx.x * blockDim.x + threadIdx.x;
#pragma unroll
  for (int k = 0; k < 2; ++k) {
    int e = tok2e[t * 2 + k];
    int slot = atomicAdd(&cnt2[e * 16], 1);
    int row = offs[e] + slot;
    rowbuf[row] = t;
    tok2row[t * 2 + k] = row;
  }
}

// ---------------- K3b: gather x rows -> compact bf16 xg ----------------
__global__ void gather_kernel(const float* __restrict__ x,
                              const int* __restrict__ rowbuf,
                              const int* __restrict__ offs,
                              unsigned short* __restrict__ xg) {
  const int row = blockIdx.x;
  if (row >= offs[16]) return;
  const int t = rowbuf[row];
  const int lane = threadIdx.x;
  float4 a = make_float4(0.f, 0.f, 0.f, 0.f), b = a;
  if (t >= 0) {
    const float4* p = (const float4*)(x + (size_t)t * D_ + lane * 8);
    a = p[0]; b = p[1];
  }
  unsigned w0 = f2bf(a.x) | (f2bf(a.y) << 16);
  unsigned w1 = f2bf(a.z) | (f2bf(a.w) << 16);
  unsigned w2 = f2bf(b.x) | (f2bf(b.y) << 16);
  unsigned w3 = f2bf(b.z) | (f2bf(b.w) << 16);
  *(uint4*)(xg + (size_t)row * D_ + lane * 8) = make_uint4(w0, w1, w2, w3);
}

// -------- K-pre: weight convert + transpose: [E][K][N] f32 -> [E][N][K] bf16 ---
template <int K, int N>
__global__ __launch_bounds__(256) void wtrans_kernel(const float* __restrict__ src,
                                                     unsigned short* __restrict__ dst) {
  __shared__ unsigned short tile[64][72];
  const int e = blockIdx.z;
  const int n0 = blockIdx.x << 6, k0 = blockIdx.y << 6;
  const int tid = threadIdx.x;
  const int tr = tid >> 4, tc = (tid & 15) << 2;
  const float* s = src + ((size_t)e * K + k0) * N + n0;
#pragma unroll
  for (int p = 0; p < 4; ++p) {
    float4 v = *(const float4*)(s + (size_t)(tr + p * 16) * N + tc);
    tile[tc + 0][tr + p * 16] = f2bf(v.x);
    tile[tc + 1][tr + p * 16] = f2bf(v.y);
    tile[tc + 2][tr + p * 16] = f2bf(v.z);
    tile[tc + 3][tr + p * 16] = f2bf(v.w);
  }
  __syncthreads();
  const int wr = tid >> 2, wc = (tid & 3) << 4;
  unsigned short* d = dst + ((size_t)e * N + n0 + wr) * K + k0 + wc;
  *(uint4*)d       = *(const uint4*)&tile[wr][wc];
  *(uint4*)(d + 8) = *(const uint4*)&tile[wr][wc + 8];
}

// ---------------- K4/K5: tiled bf16 MFMA GEMM (B pre-transposed bf16) ----------
// C[row0..+127][n0..n0+NTILE-1] = act(A[rows][K] * Bt_e[n][K]^T + bias_e)
template <int KDIM, int NTOT, int NTILE, bool GELU>
__global__ __launch_bounds__(256) void ffn_gemm(
    const unsigned short* __restrict__ A_g, const unsigned short* __restrict__ Bt_g,
    const float* __restrict__ bias_g, unsigned short* __restrict__ out_g,
    const int* __restrict__ offs, const int* __restrict__ tileoff) {
  constexpr int JN = NTILE / 32;          // b-fragments per wave
  __shared__ unsigned short As[128][72];  // +8 pad -> 2-way banks (free, m136)
  __shared__ unsigned short Bs[NTILE][72];
  const int mt = blockIdx.x;
  if (mt >= tileoff[16]) return;
  int e = 0;
  while (tileoff[e + 1] <= mt) ++e;
  const int row0 = offs[e] + ((mt - tileoff[e]) << 7);
  const int n0 = blockIdx.y * NTILE;
  const int tid = threadIdx.x;
  const int lane = tid & 63;
  const int m_off = ((tid >> 6) & 1) << 6;
  const int n_off = (tid >> 7) * (NTILE / 2);

  f32x4 acc[4][JN];
#pragma unroll
  for (int i = 0; i < 4; ++i)
#pragma unroll
    for (int j = 0; j < JN; ++j) acc[i][j] = (f32x4){0.f, 0.f, 0.f, 0.f};

  const int arow = tid >> 1, ahalf = tid & 1;
  const unsigned short* Aptr = A_g + (size_t)(row0 + arow) * KDIM + ahalf * 32;
  // B staging: every thread moves 32 bytes total per k0-iter.
  //   NTILE=128: thread owns one 32-elem half-row  (brow = tid>>1)
  //   NTILE=64 : thread owns one 16-elem quarter-row (brow = tid>>2) -> TWO uint4 stores
  int brow, bcol;
  if (NTILE == 128) { brow = tid >> 1; bcol = (tid & 1) * 32; }
  else              { brow = tid >> 2; bcol = (tid & 3) * 16; }
  const unsigned short* Bptr = Bt_g + ((size_t)e * NTOT + n0 + brow) * KDIM + bcol;

  for (int k0 = 0; k0 < KDIM; k0 += 64) {
    const uint4* asrc = (const uint4*)(Aptr + k0);
    uint4 a0 = asrc[0], a1 = asrc[1], a2 = asrc[2], a3 = asrc[3];
    const uint4* bsrc = (const uint4*)(Bptr + k0);
    uint4 b0 = bsrc[0], b1 = bsrc[1], b2, b3;
    if (NTILE == 128) { b2 = bsrc[2]; b3 = bsrc[3]; }
    uint4* adst = (uint4*)&As[arow][ahalf * 32];
    adst[0] = a0; adst[1] = a1; adst[2] = a2; adst[3] = a3;
    if (NTILE == 128) {
      uint4* bdst = (uint4*)&Bs[brow][bcol];
      bdst[0] = b0; bdst[1] = b1; bdst[2] = b2; bdst[3] = b3;
    } else {
      uint4* bdst = (uint4*)&Bs[brow][bcol];
      bdst[0] = b0; bdst[1] = b1;   // 16 elems — full quarter-row (R3 bug: only b0)
    }
    __syncthreads();
#pragma unroll
    for (int kk = 0; kk < 64; kk += 32) {
      const int kidx = kk + ((lane >> 4) << 3);
      bf16x8 af[4], bfr[JN];
#pragma unroll
      for (int i = 0; i < 4; ++i)
        af[i] = *(const bf16x8*)&As[m_off + i * 16 + (lane & 15)][kidx];
#pragma unroll
      for (int j = 0; j < JN; ++j)
        bfr[j] = *(const bf16x8*)&Bs[n_off + j * 16 + (lane & 15)][kidx];
#pragma unroll
      for (int i = 0; i < 4; ++i)
#pragma unroll
        for (int j = 0; j < JN; ++j)
          acc[i][j] = __builtin_amdgcn_mfma_f32_16x16x32_bf16(af[i], bfr[j], acc[i][j], 0, 0, 0);
    }
    __syncthreads();
  }
  // epilogue: C/D layout col=lane&15, row=quad*4+reg (m89-verified)
  const float* bias = bias_g + (size_t)e * NTOT;
  const int quad = lane >> 4, lcol = lane & 15;
#pragma unroll
  for (int j = 0; j < JN; ++j) {
    const int col = n0 + n_off + j * 16 + lcol;
    const float bv = bias[col];
#pragma unroll
    for (int i = 0; i < 4; ++i) {
      const int rbase = row0 + m_off + i * 16 + (quad << 2);
      f32x4 v = acc[i][j];
#pragma unroll
      for (int r = 0; r < 4; ++r) {
        float y = v[r] + bv;
        if (GELU) y = 0.5f * y * (1.f + erff(y * 0.70710678118f));
        out_g[(size_t)(rbase + r) * NTOT + col] = f2bf(y);
      }
    }
  }
}

// ---------------- K6: combine the two expert rows per token ----------------
__global__ void combine_kernel(const unsigned short* __restrict__ ybuf,
                               const int* __restrict__ tok2row,
                               float* __restrict__ out) {
  const int t = blockIdx.x, lane = threadIdx.x;
  const int rA = tok2row[t * 2], rB = tok2row[t * 2 + 1];
  const uint4 va = *(const uint4*)(ybuf + (size_t)rA * D_ + lane * 8);
  const uint4 vb = *(const uint4*)(ybuf + (size_t)rB * D_ + lane * 8);
  const unsigned short* pa = (const unsigned short*)&va;
  const unsigned short* pb = (const unsigned short*)&vb;
  float o[8];
#pragma unroll
  for (int i = 0; i < 8; ++i) o[i] = bf2f(pa[i]) + bf2f(pb[i]);
  float4* po = (float4*)(out + (size_t)t * D_ + lane * 8);
  po[0] = make_float4(o[0], o[1], o[2], o[3]);
  po[1] = make_float4(o[4], o[5], o[6], o[7]);
}

extern "C" void kernel_launch(void* const* d_in, const int* in_sizes, int n_in,
                              void* d_out, int out_size, void* d_ws, size_t ws_size,
                              hipStream_t stream) {
  const float* x  = (const float*)d_in[0];
  const float* Wg = (const float*)d_in[1];
  const float* bg = (const float*)d_in[2];
  const float* W1 = (const float*)d_in[3];
  const float* b1 = (const float*)d_in[4];
  const float* W2 = (const float*)d_in[5];
  const float* b2 = (const float*)d_in[6];
  float* out = (float*)d_out;
  char* ws = (char*)d_ws;

  // ws layout (84 MB):
  int* cnt2    = (int*)(ws);                  // 16 experts x 16-int stride
  int* offs    = (int*)(ws + 2048);
  int* tileoff = (int*)(ws + 3072);
  int* tok2e   = (int*)(ws + 4096);
  int* tok2row = (int*)(ws + 4096 + 32768);
  int* rowbuf  = (int*)(ws + 4096 + 65536);
  unsigned short* xg   = (unsigned short*)(ws + (1 << 20));   // 10 MB
  unsigned short* ybuf = xg;                                  // reuse after GEMM1
  unsigned short* hbuf = (unsigned short*)(ws + (size_t)(12 << 20));  // 40 MB
  unsigned short* Wt   = (unsigned short*)(ws + (size_t)(52 << 20));  // 32 MB, W1t then W2t

  gate_kernel<<<T_ / 4, 256, 0, stream>>>(x, Wg, bg, out, tok2e);
  count_kernel<<<1, 256, 0, stream>>>(tok2e, cnt2, offs, tileoff, rowbuf);
  scatter_kernel<<<T_ / 256, 256, 0, stream>>>(tok2e, cnt2, offs, rowbuf, tok2row);
  gather_kernel<<<RCAP, 64, 0, stream>>>(x, rowbuf, offs, xg);
  // W1 [E][512][2048] -> W1t [E][2048][512] bf16
  wtrans_kernel<D_, H_><<<dim3(H_ / 64, D_ / 64, E_), 256, 0, stream>>>(W1, Wt);
  // GEMM1: h = gelu(xg @ W1 + b1) -> hbuf    (K=512, N=2048, NTILE=128)
  ffn_gemm<512, 2048, 128, true><<<dim3(80, 16), 256, 0, stream>>>(xg, Wt, b1, hbuf, offs, tileoff);
  // W2 [E][2048][512] -> W2t [E][512][2048] bf16 (reuses Wt slot)
  wtrans_kernel<H_, D_><<<dim3(D_ / 64, H_ / 64, E_), 256, 0, stream>>>(W2, Wt);
  // GEMM2: y = hbuf @ W2 + b2 -> ybuf        (K=2048, N=512, NTILE=64 -> 640 blocks)
  ffn_gemm<2048, 512, 64, false><<<dim3(80, 8), 256, 0, stream>>>(hbuf, Wt, b2, ybuf, offs, tileoff);
  combine_kernel<<<T_, 64, 0, stream>>>(ybuf, tok2row, out);
}

// Round 5
// 294.209 us; speedup vs baseline: 1.4859x; 1.0725x over previous
//
#include <hip/hip_runtime.h>
#include <math.h>

#define T_ 4096
#define D_ 512
#define H_ 2048
#define E_ 16
#define RCAP 10240   // max padded rows: 8192 + 16*128

typedef short bf16x8 __attribute__((ext_vector_type(8)));
typedef float f32x4 __attribute__((ext_vector_type(4)));

__device__ __forceinline__ unsigned short f2bf(float f) {
  union { float f; unsigned u; } v; v.f = f;
  unsigned r = v.u + 0x7fffu + ((v.u >> 16) & 1u);
  return (unsigned short)(r >> 16);
}
__device__ __forceinline__ float bf2f(unsigned short u) {
  union { unsigned u; float f; } v; v.u = ((unsigned)u) << 16;
  return v.f;
}
// async global->LDS, 16B per lane; lds dest = wave-uniform base + lane*16 (m97/m104)
__device__ __forceinline__ void gload_lds16(const unsigned short* g, unsigned short* l) {
  __builtin_amdgcn_global_load_lds((const __attribute__((address_space(1))) void*)g,
                                   (__attribute__((address_space(3))) void*)l, 16, 0, 0);
}

// ---------------- K1: gate (one wave per token; Wg staged in LDS) ----------------
__global__ __launch_bounds__(256) void gate_kernel(const float* __restrict__ x,
                                                   const float* __restrict__ Wg,
                                                   const float* __restrict__ bg,
                                                   float* __restrict__ out,
                                                   int* __restrict__ tok2e) {
  __shared__ float wgl[D_ * E_];  // 32 KB
  for (int i = threadIdx.x; i < D_ * E_ / 4; i += 256)
    *(float4*)&wgl[i * 4] = ((const float4*)Wg)[i];
  __syncthreads();
  const int lane = threadIdx.x & 63;
  const int t = blockIdx.x * 4 + (threadIdx.x >> 6);
  const int e = lane & 15, q = lane >> 4;
  const float4* x4 = (const float4*)(x + (size_t)t * D_ + q * 128);
  float acc = 0.f;
#pragma unroll 4
  for (int i = 0; i < 32; ++i) {
    float4 v = x4[i];
    const float* wp = &wgl[(q * 128 + i * 4) * E_ + e];
    acc += v.x * wp[0];
    acc += v.y * wp[E_];
    acc += v.z * wp[2 * E_];
    acc += v.w * wp[3 * E_];
  }
  acc += __shfl_xor(acc, 16);
  acc += __shfl_xor(acc, 32);
  const float logit = acc + bg[e];
  float v1 = logit; int i1 = e;
#pragma unroll
  for (int s = 1; s < 16; s <<= 1) {
    float ov = __shfl_xor(v1, s); int oi = __shfl_xor(i1, s);
    if (ov > v1 || (ov == v1 && oi < i1)) { v1 = ov; i1 = oi; }
  }
  float v2 = (e == i1) ? -INFINITY : logit; int i2 = e;
#pragma unroll
  for (int s = 1; s < 16; s <<= 1) {
    float ov = __shfl_xor(v2, s); int oi = __shfl_xor(i2, s);
    if (ov > v2 || (ov == v2 && oi < i2)) { v2 = ov; i2 = oi; }
  }
  if (lane == 0) {
    const float ed = __expf(v2 - v1);
    const float inv = 1.f / (1.f + ed);
    const size_t gidx = (size_t)T_ * D_;
    out[gidx + t * 2]     = (float)i1;
    out[gidx + t * 2 + 1] = (float)i2;
    out[gidx + T_ * 2 + t * 2]     = inv;
    out[gidx + T_ * 2 + t * 2 + 1] = ed * inv;
    tok2e[t * 2] = i1; tok2e[t * 2 + 1] = i2;
  }
}

// ------- K2: histogram + offsets (LDS atomics; one block) + buffer init -------
__global__ void count_kernel(const int* __restrict__ tok2e,
                             int* __restrict__ cnt2,
                             int* __restrict__ offs, int* __restrict__ tileoff,
                             int* __restrict__ rowbuf) {
  __shared__ int h[E_];
  if (threadIdx.x < E_) h[threadIdx.x] = 0;
  __syncthreads();
  for (int i = threadIdx.x; i < 2 * T_; i += 256) atomicAdd(&h[tok2e[i]], 1);
  __syncthreads();
  if (threadIdx.x == 0) {
    int o = 0, to = 0;
    offs[0] = 0; tileoff[0] = 0;
    for (int e = 0; e < E_; ++e) {
      int mt = (h[e] + 127) >> 7;
      o += mt << 7; to += mt;
      offs[e + 1] = o; tileoff[e + 1] = to;
    }
  }
  for (int i = threadIdx.x; i < E_ * 16; i += 256) cnt2[i] = 0;
  for (int i = threadIdx.x; i < RCAP; i += 256) rowbuf[i] = -1;
}

// ---------------- K3a: scatter (cnt2 padded to one line/expert) ----------------
__global__ void scatter_kernel(const int* __restrict__ tok2e, int* __restrict__ cnt2,
                               const int* __restrict__ offs, int* __restrict__ rowbuf,
                               int* __restrict__ tok2row) {
  const int t = blockIdx.x * blockDim.x + threadIdx.x;
#pragma unroll
  for (int k = 0; k < 2; ++k) {
    int e = tok2e[t * 2 + k];
    int slot = atomicAdd(&cnt2[e * 16], 1);
    int row = offs[e] + slot;
    rowbuf[row] = t;
    tok2row[t * 2 + k] = row;
  }
}

// ---------------- K3b: gather x rows -> compact bf16 xg ----------------
__global__ void gather_kernel(const float* __restrict__ x,
                              const int* __restrict__ rowbuf,
                              const int* __restrict__ offs,
                              unsigned short* __restrict__ xg) {
  const int row = blockIdx.x;
  if (row >= offs[16]) return;
  const int t = rowbuf[row];
  const int lane = threadIdx.x;
  float4 a = make_float4(0.f, 0.f, 0.f, 0.f), b = a;
  if (t >= 0) {
    const float4* p = (const float4*)(x + (size_t)t * D_ + lane * 8);
    a = p[0]; b = p[1];
  }
  unsigned w0 = f2bf(a.x) | (f2bf(a.y) << 16);
  unsigned w1 = f2bf(a.z) | (f2bf(a.w) << 16);
  unsigned w2 = f2bf(b.x) | (f2bf(b.y) << 16);
  unsigned w3 = f2bf(b.z) | (f2bf(b.w) << 16);
  *(uint4*)(xg + (size_t)row * D_ + lane * 8) = make_uint4(w0, w1, w2, w3);
}

// -------- K-pre: weight convert + transpose: [E][K][N] f32 -> [E][N][K] bf16 ---
template <int K, int N>
__global__ __launch_bounds__(256) void wtrans_kernel(const float* __restrict__ src,
                                                     unsigned short* __restrict__ dst) {
  __shared__ unsigned short tile[64][72];
  const int e = blockIdx.z;
  const int n0 = blockIdx.x << 6, k0 = blockIdx.y << 6;
  const int tid = threadIdx.x;
  const int tr = tid >> 4, tc = (tid & 15) << 2;
  const float* s = src + ((size_t)e * K + k0) * N + n0;
#pragma unroll
  for (int p = 0; p < 4; ++p) {
    float4 v = *(const float4*)(s + (size_t)(tr + p * 16) * N + tc);
    tile[tc + 0][tr + p * 16] = f2bf(v.x);
    tile[tc + 1][tr + p * 16] = f2bf(v.y);
    tile[tc + 2][tr + p * 16] = f2bf(v.z);
    tile[tc + 3][tr + p * 16] = f2bf(v.w);
  }
  __syncthreads();
  const int wr = tid >> 2, wc = (tid & 3) << 4;
  unsigned short* d = dst + ((size_t)e * N + n0 + wr) * K + k0 + wc;
  *(uint4*)d       = *(const uint4*)&tile[wr][wc];
  *(uint4*)(d + 8) = *(const uint4*)&tile[wr][wc + 8];
}

// ---------------- K4/K5: tiled bf16 MFMA GEMM, global_load_lds staging ----------
// LDS tiles are UNPADDED [rows][64] (global_load_lds requires lane-contiguous
// dest, m104). Bank conflicts on fragment reads broken by XOR swizzle of 16B
// column-blocks: LDS[r][c] holds global[r][c ^ (r&7)] (both sides use it).
template <int KDIM, int NTOT, int NTILE, bool GELU>
__global__ __launch_bounds__(256) void ffn_gemm(
    const unsigned short* __restrict__ A_g, const unsigned short* __restrict__ Bt_g,
    const float* __restrict__ bias_g, unsigned short* __restrict__ out_g,
    const int* __restrict__ offs, const int* __restrict__ tileoff) {
  constexpr int JN = NTILE / 32;                 // b-fragments per wave
  constexpr int BRPW = NTILE / 4;                // B rows staged per wave
  __shared__ unsigned short As[128 * 64];        // 16 KB
  __shared__ unsigned short Bs[NTILE * 64];      // 16 or 8 KB
  const int mt = blockIdx.x;
  if (mt >= tileoff[16]) return;
  int e = 0;
  while (tileoff[e + 1] <= mt) ++e;
  const int row0 = offs[e] + ((mt - tileoff[e]) << 7);
  const int n0 = blockIdx.y * NTILE;
  const int tid = threadIdx.x;
  const int lane = tid & 63;
  const int w = tid >> 6;
  const int m_off = (w & 1) << 6;
  const int n_off = (tid >> 7) * (NTILE / 2);

  f32x4 acc[4][JN];
#pragma unroll
  for (int i = 0; i < 4; ++i)
#pragma unroll
    for (int j = 0; j < JN; ++j) acc[i][j] = (f32x4){0.f, 0.f, 0.f, 0.f};

  // staging addressing: inst j covers 8 rows; lane -> row j*8 + (lane>>3),
  // global col-block (lane&7)^(row&7); HW writes lds base + lane*16.
  const int r_in = lane >> 3;
  const int cbg = (lane & 7) ^ r_in;
  const unsigned short* gA = A_g + (size_t)(row0 + w * 32 + r_in) * KDIM + cbg * 8;
  const unsigned short* gB = Bt_g + ((size_t)e * NTOT + n0 + w * BRPW + r_in) * KDIM + cbg * 8;
  unsigned short* lA = &As[w * 32 * 64];
  unsigned short* lB = &Bs[w * BRPW * 64];

  const int q = lane >> 4, fr = lane & 15;

  for (int k0 = 0; k0 < KDIM; k0 += 64) {
#pragma unroll
    for (int j = 0; j < 4; ++j)
      gload_lds16(gA + (size_t)j * 8 * KDIM + k0, lA + j * 8 * 64);
#pragma unroll
    for (int j = 0; j < BRPW / 8; ++j)
      gload_lds16(gB + (size_t)j * 8 * KDIM + k0, lB + j * 8 * 64);
    __syncthreads();
#pragma unroll
    for (int kk = 0; kk < 64; kk += 32) {
      bf16x8 af[4], bfr[JN];
#pragma unroll
      for (int i = 0; i < 4; ++i) {
        const int r = m_off + i * 16 + fr;
        const int sw = ((((kk >> 3) + q) ^ (r & 7)) << 3);
        af[i] = *(const bf16x8*)&As[r * 64 + sw];
      }
#pragma unroll
      for (int j = 0; j < JN; ++j) {
        const int r = n_off + j * 16 + fr;
        const int sw = ((((kk >> 3) + q) ^ (r & 7)) << 3);
        bfr[j] = *(const bf16x8*)&Bs[r * 64 + sw];
      }
#pragma unroll
      for (int i = 0; i < 4; ++i)
#pragma unroll
        for (int j = 0; j < JN; ++j)
          acc[i][j] = __builtin_amdgcn_mfma_f32_16x16x32_bf16(af[i], bfr[j], acc[i][j], 0, 0, 0);
    }
    __syncthreads();
  }
  // epilogue: C/D layout col=lane&15, row=quad*4+reg (m89-verified)
  const float* bias = bias_g + (size_t)e * NTOT;
#pragma unroll
  for (int j = 0; j < JN; ++j) {
    const int col = n0 + n_off + j * 16 + fr;
    const float bv = bias[col];
#pragma unroll
    for (int i = 0; i < 4; ++i) {
      const int rbase = row0 + m_off + i * 16 + (q << 2);
      f32x4 v = acc[i][j];
#pragma unroll
      for (int r = 0; r < 4; ++r) {
        float y = v[r] + bv;
        if (GELU) y = 0.5f * y * (1.f + erff(y * 0.70710678118f));
        out_g[(size_t)(rbase + r) * NTOT + col] = f2bf(y);
      }
    }
  }
}

// ---------------- K6: combine the two expert rows per token ----------------
__global__ void combine_kernel(const unsigned short* __restrict__ ybuf,
                               const int* __restrict__ tok2row,
                               float* __restrict__ out) {
  const int t = blockIdx.x, lane = threadIdx.x;
  const int rA = tok2row[t * 2], rB = tok2row[t * 2 + 1];
  const uint4 va = *(const uint4*)(ybuf + (size_t)rA * D_ + lane * 8);
  const uint4 vb = *(const uint4*)(ybuf + (size_t)rB * D_ + lane * 8);
  const unsigned short* pa = (const unsigned short*)&va;
  const unsigned short* pb = (const unsigned short*)&vb;
  float o[8];
#pragma unroll
  for (int i = 0; i < 8; ++i) o[i] = bf2f(pa[i]) + bf2f(pb[i]);
  float4* po = (float4*)(out + (size_t)t * D_ + lane * 8);
  po[0] = make_float4(o[0], o[1], o[2], o[3]);
  po[1] = make_float4(o[4], o[5], o[6], o[7]);
}

extern "C" void kernel_launch(void* const* d_in, const int* in_sizes, int n_in,
                              void* d_out, int out_size, void* d_ws, size_t ws_size,
                              hipStream_t stream) {
  const float* x  = (const float*)d_in[0];
  const float* Wg = (const float*)d_in[1];
  const float* bg = (const float*)d_in[2];
  const float* W1 = (const float*)d_in[3];
  const float* b1 = (const float*)d_in[4];
  const float* W2 = (const float*)d_in[5];
  const float* b2 = (const float*)d_in[6];
  float* out = (float*)d_out;
  char* ws = (char*)d_ws;

  // ws layout (84 MB):
  int* cnt2    = (int*)(ws);                  // 16 experts x 16-int stride
  int* offs    = (int*)(ws + 2048);
  int* tileoff = (int*)(ws + 3072);
  int* tok2e   = (int*)(ws + 4096);
  int* tok2row = (int*)(ws + 4096 + 32768);
  int* rowbuf  = (int*)(ws + 4096 + 65536);
  unsigned short* xg   = (unsigned short*)(ws + (1 << 20));   // 10 MB
  unsigned short* ybuf = xg;                                  // reuse after GEMM1
  unsigned short* hbuf = (unsigned short*)(ws + (size_t)(12 << 20));  // 40 MB
  unsigned short* Wt   = (unsigned short*)(ws + (size_t)(52 << 20));  // 32 MB, W1t then W2t

  gate_kernel<<<T_ / 4, 256, 0, stream>>>(x, Wg, bg, out, tok2e);
  count_kernel<<<1, 256, 0, stream>>>(tok2e, cnt2, offs, tileoff, rowbuf);
  scatter_kernel<<<T_ / 256, 256, 0, stream>>>(tok2e, cnt2, offs, rowbuf, tok2row);
  gather_kernel<<<RCAP, 64, 0, stream>>>(x, rowbuf, offs, xg);
  // W1 [E][512][2048] -> W1t [E][2048][512] bf16
  wtrans_kernel<D_, H_><<<dim3(H_ / 64, D_ / 64, E_), 256, 0, stream>>>(W1, Wt);
  // GEMM1: h = gelu(xg @ W1 + b1) -> hbuf    (K=512, N=2048, NTILE=128)
  ffn_gemm<512, 2048, 128, true><<<dim3(80, 16), 256, 0, stream>>>(xg, Wt, b1, hbuf, offs, tileoff);
  // W2 [E][2048][512] -> W2t [E][512][2048] bf16 (reuses Wt slot)
  wtrans_kernel<H_, D_><<<dim3(D_ / 64, H_ / 64, E_), 256, 0, stream>>>(W2, Wt);
  // GEMM2: y = hbuf @ W2 + b2 -> ybuf        (K=2048, N=512, NTILE=64 -> 640 blocks)
  ffn_gemm<2048, 512, 64, false><<<dim3(80, 8), 256, 0, stream>>>(hbuf, Wt, b2, ybuf, offs, tileoff);
  combine_kernel<<<T_, 64, 0, stream>>>(ybuf, tok2row, out);
}

// Round 6
// 280.796 us; speedup vs baseline: 1.5569x; 1.0478x over previous
//
#include <hip/hip_runtime.h>
#include <math.h>

#define T_ 4096
#define D_ 512
#define H_ 2048
#define E_ 16
#define RCAP 10240   // max padded rows: 8192 + 16*128

typedef short bf16x8 __attribute__((ext_vector_type(8)));
typedef float f32x4 __attribute__((ext_vector_type(4)));

__device__ __forceinline__ unsigned short f2bf(float f) {
  union { float f; unsigned u; } v; v.f = f;
  unsigned r = v.u + 0x7fffu + ((v.u >> 16) & 1u);
  return (unsigned short)(r >> 16);
}
__device__ __forceinline__ float bf2f(unsigned short u) {
  union { unsigned u; float f; } v; v.u = ((unsigned)u) << 16;
  return v.f;
}
// async global->LDS, 16B per lane; lds dest = wave-uniform base + lane*16 (m97/m104)
__device__ __forceinline__ void gload_lds16(const unsigned short* g, unsigned short* l) {
  __builtin_amdgcn_global_load_lds((const __attribute__((address_space(1))) void*)g,
                                   (__attribute__((address_space(3))) void*)l, 16, 0, 0);
}
// tanh-form gelu = x * sigmoid(2s); ~8 VALU inst vs ~30 for erff. NaN-free.
__device__ __forceinline__ float gelu_fast(float y) {
  float s2 = 1.5957691216f * (y + 0.044715f * y * y * y);
  return y * __builtin_amdgcn_rcpf(1.f + __expf(-s2));
}

// ---------------- K1: gate (one wave per token; Wg staged in LDS) ----------------
__global__ __launch_bounds__(256) void gate_kernel(const float* __restrict__ x,
                                                   const float* __restrict__ Wg,
                                                   const float* __restrict__ bg,
                                                   float* __restrict__ out,
                                                   int* __restrict__ tok2e) {
  __shared__ float wgl[D_ * E_];  // 32 KB
  for (int i = threadIdx.x; i < D_ * E_ / 4; i += 256)
    *(float4*)&wgl[i * 4] = ((const float4*)Wg)[i];
  __syncthreads();
  const int lane = threadIdx.x & 63;
  const int t = blockIdx.x * 4 + (threadIdx.x >> 6);
  const int e = lane & 15, q = lane >> 4;
  const float4* x4 = (const float4*)(x + (size_t)t * D_ + q * 128);
  float acc = 0.f;
#pragma unroll 4
  for (int i = 0; i < 32; ++i) {
    float4 v = x4[i];
    const float* wp = &wgl[(q * 128 + i * 4) * E_ + e];
    acc += v.x * wp[0];
    acc += v.y * wp[E_];
    acc += v.z * wp[2 * E_];
    acc += v.w * wp[3 * E_];
  }
  acc += __shfl_xor(acc, 16);
  acc += __shfl_xor(acc, 32);
  const float logit = acc + bg[e];
  float v1 = logit; int i1 = e;
#pragma unroll
  for (int s = 1; s < 16; s <<= 1) {
    float ov = __shfl_xor(v1, s); int oi = __shfl_xor(i1, s);
    if (ov > v1 || (ov == v1 && oi < i1)) { v1 = ov; i1 = oi; }
  }
  float v2 = (e == i1) ? -INFINITY : logit; int i2 = e;
#pragma unroll
  for (int s = 1; s < 16; s <<= 1) {
    float ov = __shfl_xor(v2, s); int oi = __shfl_xor(i2, s);
    if (ov > v2 || (ov == v2 && oi < i2)) { v2 = ov; i2 = oi; }
  }
  if (lane == 0) {
    const float ed = __expf(v2 - v1);
    const float inv = 1.f / (1.f + ed);
    const size_t gidx = (size_t)T_ * D_;
    out[gidx + t * 2]     = (float)i1;
    out[gidx + t * 2 + 1] = (float)i2;
    out[gidx + T_ * 2 + t * 2]     = inv;
    out[gidx + T_ * 2 + t * 2 + 1] = ed * inv;
    tok2e[t * 2] = i1; tok2e[t * 2 + 1] = i2;
  }
}

// ------- K2: histogram + offsets (LDS atomics; one block) -------
__global__ void count_kernel(const int* __restrict__ tok2e,
                             int* __restrict__ cnt2,
                             int* __restrict__ offs, int* __restrict__ tileoff) {
  __shared__ int h[E_];
  if (threadIdx.x < E_) h[threadIdx.x] = 0;
  __syncthreads();
  for (int i = threadIdx.x; i < 2 * T_; i += 256) atomicAdd(&h[tok2e[i]], 1);
  __syncthreads();
  if (threadIdx.x == 0) {
    int o = 0, to = 0;
    offs[0] = 0; tileoff[0] = 0;
    for (int e = 0; e < E_; ++e) {
      int mt = (h[e] + 127) >> 7;
      o += mt << 7; to += mt;
      offs[e + 1] = o; tileoff[e + 1] = to;
    }
  }
  for (int i = threadIdx.x; i < E_ * 16; i += 256) cnt2[i] = 0;
}

// ------- K3: fused scatter+gather — one wave per token writes both xg rows -----
// Pad rows stay 0xAA-poisoned (tiny negative bf16, NaN-free); their C rows are
// never read by combine, and MFMA mixes nothing across A rows.
__global__ __launch_bounds__(256) void scatgath_kernel(
    const float* __restrict__ x, const int* __restrict__ tok2e,
    int* __restrict__ cnt2, const int* __restrict__ offs,
    int* __restrict__ tok2row, unsigned short* __restrict__ xg) {
  const int lane = threadIdx.x & 63;
  const int t = blockIdx.x * 4 + (threadIdx.x >> 6);
  int rA = 0, rB = 0;
  if (lane == 0) {
    const int e1 = tok2e[t * 2], e2 = tok2e[t * 2 + 1];
    rA = offs[e1] + atomicAdd(&cnt2[e1 * 16], 1);
    rB = offs[e2] + atomicAdd(&cnt2[e2 * 16], 1);
    tok2row[t * 2] = rA; tok2row[t * 2 + 1] = rB;
  }
  rA = __shfl(rA, 0); rB = __shfl(rB, 0);
  const float4* p = (const float4*)(x + (size_t)t * D_ + lane * 8);
  const float4 a = p[0], b = p[1];
  const unsigned w0 = f2bf(a.x) | (f2bf(a.y) << 16);
  const unsigned w1 = f2bf(a.z) | (f2bf(a.w) << 16);
  const unsigned w2 = f2bf(b.x) | (f2bf(b.y) << 16);
  const unsigned w3 = f2bf(b.z) | (f2bf(b.w) << 16);
  const uint4 val = make_uint4(w0, w1, w2, w3);
  *(uint4*)(xg + (size_t)rA * D_ + lane * 8) = val;
  *(uint4*)(xg + (size_t)rB * D_ + lane * 8) = val;
}

// -------- K-pre: weight convert + transpose: [E][K][N] f32 -> [E][N][K] bf16 ---
template <int K, int N>
__global__ __launch_bounds__(256) void wtrans_kernel(const float* __restrict__ src,
                                                     unsigned short* __restrict__ dst) {
  __shared__ unsigned short tile[64][72];
  const int e = blockIdx.z;
  const int n0 = blockIdx.x << 6, k0 = blockIdx.y << 6;
  const int tid = threadIdx.x;
  const int tr = tid >> 4, tc = (tid & 15) << 2;
  const float* s = src + ((size_t)e * K + k0) * N + n0;
#pragma unroll
  for (int p = 0; p < 4; ++p) {
    float4 v = *(const float4*)(s + (size_t)(tr + p * 16) * N + tc);
    tile[tc + 0][tr + p * 16] = f2bf(v.x);
    tile[tc + 1][tr + p * 16] = f2bf(v.y);
    tile[tc + 2][tr + p * 16] = f2bf(v.z);
    tile[tc + 3][tr + p * 16] = f2bf(v.w);
  }
  __syncthreads();
  const int wr = tid >> 2, wc = (tid & 3) << 4;
  unsigned short* d = dst + ((size_t)e * N + n0 + wr) * K + k0 + wc;
  *(uint4*)d       = *(const uint4*)&tile[wr][wc];
  *(uint4*)(d + 8) = *(const uint4*)&tile[wr][wc + 8];
}

// ---------------- K4/K5: tiled bf16 MFMA GEMM, global_load_lds staging ----------
// LDS tiles UNPADDED [rows][64]; XOR swizzle of 16B column-blocks breaks bank
// conflicts (stage and read agree). Epilogue bounces C through LDS (per-wave
// region, XOR-swizzled) for 128B-coalesced global stores.
template <int KDIM, int NTOT, int NTILE, bool GELU>
__global__ __launch_bounds__(256) void ffn_gemm(
    const unsigned short* __restrict__ A_g, const unsigned short* __restrict__ Bt_g,
    const float* __restrict__ bias_g, unsigned short* __restrict__ out_g,
    const int* __restrict__ offs, const int* __restrict__ tileoff) {
  constexpr int JN = NTILE / 32;                 // b-fragments per wave
  constexpr int BRPW = NTILE / 4;                // B rows staged per wave
  __shared__ unsigned short As[128 * 64];        // 16 KB
  __shared__ unsigned short Bs[NTILE * 64];      // 16 or 8 KB
  const int mt = blockIdx.x;
  if (mt >= tileoff[16]) return;
  int e = 0;
  while (tileoff[e + 1] <= mt) ++e;
  const int row0 = offs[e] + ((mt - tileoff[e]) << 7);
  const int n0 = blockIdx.y * NTILE;
  const int tid = threadIdx.x;
  const int lane = tid & 63;
  const int w = tid >> 6;
  const int m_off = (w & 1) << 6;
  const int n_off = (tid >> 7) * (NTILE / 2);

  f32x4 acc[4][JN];
#pragma unroll
  for (int i = 0; i < 4; ++i)
#pragma unroll
    for (int j = 0; j < JN; ++j) acc[i][j] = (f32x4){0.f, 0.f, 0.f, 0.f};

  const int r_in = lane >> 3;
  const int cbg = (lane & 7) ^ r_in;
  const unsigned short* gA = A_g + (size_t)(row0 + w * 32 + r_in) * KDIM + cbg * 8;
  const unsigned short* gB = Bt_g + ((size_t)e * NTOT + n0 + w * BRPW + r_in) * KDIM + cbg * 8;
  unsigned short* lA = &As[w * 32 * 64];
  unsigned short* lB = &Bs[w * BRPW * 64];

  const int q = lane >> 4, fr = lane & 15;

  for (int k0 = 0; k0 < KDIM; k0 += 64) {
#pragma unroll
    for (int j = 0; j < 4; ++j)
      gload_lds16(gA + (size_t)j * 8 * KDIM + k0, lA + j * 8 * 64);
#pragma unroll
    for (int j = 0; j < BRPW / 8; ++j)
      gload_lds16(gB + (size_t)j * 8 * KDIM + k0, lB + j * 8 * 64);
    __syncthreads();
#pragma unroll
    for (int kk = 0; kk < 64; kk += 32) {
      bf16x8 af[4], bfr[JN];
#pragma unroll
      for (int i = 0; i < 4; ++i) {
        const int r = m_off + i * 16 + fr;
        const int sw = ((((kk >> 3) + q) ^ (r & 7)) << 3);
        af[i] = *(const bf16x8*)&As[r * 64 + sw];
      }
#pragma unroll
      for (int j = 0; j < JN; ++j) {
        const int r = n_off + j * 16 + fr;
        const int sw = ((((kk >> 3) + q) ^ (r & 7)) << 3);
        bfr[j] = *(const bf16x8*)&Bs[r * 64 + sw];
      }
#pragma unroll
      for (int i = 0; i < 4; ++i)
#pragma unroll
        for (int j = 0; j < JN; ++j)
          acc[i][j] = __builtin_amdgcn_mfma_f32_16x16x32_bf16(af[i], bfr[j], acc[i][j], 0, 0, 0);
    }
    __syncthreads();
  }

  // ---- epilogue: C/D layout col=lane&15, row=quad*4+reg (m89) ----
  // Bounce through per-wave LDS region [64][W], 16B blocks XOR-swizzled by
  // (row & (LB-1)) so readback rows spread across all banks.
  constexpr int W = NTILE / 2;   // cols per wave
  constexpr int LB = W / 8;      // 16B blocks per row (8 or 4)
  unsigned short* cbase;
  if (NTILE == 128) cbase = (w < 2) ? &As[w * 4096] : &Bs[(w - 2) * 4096];
  else              cbase = &As[w * 2048];
  const float* bias = bias_g + (size_t)e * NTOT;
#pragma unroll
  for (int j = 0; j < JN; ++j) {
    const float bv = bias[n0 + n_off + j * 16 + fr];
#pragma unroll
    for (int i = 0; i < 4; ++i) {
      f32x4 v = acc[i][j];
#pragma unroll
      for (int r = 0; r < 4; ++r) {
        float y = v[r] + bv;
        if (GELU) y = gelu_fast(y);
        const int lr = i * 16 + (q << 2) + r;
        const int lc = j * 16 + fr;
        const int phys = (lc >> 3) ^ (lr & (LB - 1));
        cbase[lr * W + phys * 8 + (lc & 7)] = f2bf(y);
      }
    }
  }
  __syncthreads();  // order LDS writes before cross-lane readback
#pragma unroll
  for (int it = 0; it < LB; ++it) {
    const int lr = it * (64 / LB) + (lane / LB);
    const int bl = lane % LB;                 // logical 16B block
    const int phys = bl ^ (lr & (LB - 1));
    const uint4 val = *(const uint4*)&cbase[lr * W + phys * 8];
    *(uint4*)&out_g[(size_t)(row0 + m_off + lr) * NTOT + n0 + n_off + bl * 8] = val;
  }
}

// ---------------- K6: combine the two expert rows per token ----------------
__global__ void combine_kernel(const unsigned short* __restrict__ ybuf,
                               const int* __restrict__ tok2row,
                               float* __restrict__ out) {
  const int t = blockIdx.x, lane = threadIdx.x;
  const int rA = tok2row[t * 2], rB = tok2row[t * 2 + 1];
  const uint4 va = *(const uint4*)(ybuf + (size_t)rA * D_ + lane * 8);
  const uint4 vb = *(const uint4*)(ybuf + (size_t)rB * D_ + lane * 8);
  const unsigned short* pa = (const unsigned short*)&va;
  const unsigned short* pb = (const unsigned short*)&vb;
  float o[8];
#pragma unroll
  for (int i = 0; i < 8; ++i) o[i] = bf2f(pa[i]) + bf2f(pb[i]);
  float4* po = (float4*)(out + (size_t)t * D_ + lane * 8);
  po[0] = make_float4(o[0], o[1], o[2], o[3]);
  po[1] = make_float4(o[4], o[5], o[6], o[7]);
}

extern "C" void kernel_launch(void* const* d_in, const int* in_sizes, int n_in,
                              void* d_out, int out_size, void* d_ws, size_t ws_size,
                              hipStream_t stream) {
  const float* x  = (const float*)d_in[0];
  const float* Wg = (const float*)d_in[1];
  const float* bg = (const float*)d_in[2];
  const float* W1 = (const float*)d_in[3];
  const float* b1 = (const float*)d_in[4];
  const float* W2 = (const float*)d_in[5];
  const float* b2 = (const float*)d_in[6];
  float* out = (float*)d_out;
  char* ws = (char*)d_ws;

  // ws layout (84 MB):
  int* cnt2    = (int*)(ws);                  // 16 experts x 16-int stride
  int* offs    = (int*)(ws + 2048);
  int* tileoff = (int*)(ws + 3072);
  int* tok2e   = (int*)(ws + 4096);
  int* tok2row = (int*)(ws + 4096 + 32768);
  unsigned short* xg   = (unsigned short*)(ws + (1 << 20));   // 10 MB
  unsigned short* ybuf = xg;                                  // reuse after GEMM1
  unsigned short* hbuf = (unsigned short*)(ws + (size_t)(12 << 20));  // 40 MB
  unsigned short* Wt   = (unsigned short*)(ws + (size_t)(52 << 20));  // 32 MB, W1t then W2t

  gate_kernel<<<T_ / 4, 256, 0, stream>>>(x, Wg, bg, out, tok2e);
  count_kernel<<<1, 256, 0, stream>>>(tok2e, cnt2, offs, tileoff);
  scatgath_kernel<<<T_ / 4, 256, 0, stream>>>(x, tok2e, cnt2, offs, tok2row, xg);
  // W1 [E][512][2048] -> W1t [E][2048][512] bf16
  wtrans_kernel<D_, H_><<<dim3(H_ / 64, D_ / 64, E_), 256, 0, stream>>>(W1, Wt);
  // GEMM1: h = gelu(xg @ W1 + b1) -> hbuf    (K=512, N=2048, NTILE=128)
  ffn_gemm<512, 2048, 128, true><<<dim3(80, 16), 256, 0, stream>>>(xg, Wt, b1, hbuf, offs, tileoff);
  // W2 [E][2048][512] -> W2t [E][512][2048] bf16 (reuses Wt slot)
  wtrans_kernel<H_, D_><<<dim3(D_ / 64, H_ / 64, E_), 256, 0, stream>>>(W2, Wt);
  // GEMM2: y = hbuf @ W2 + b2 -> ybuf        (K=2048, N=512, NTILE=64 -> 640 blocks)
  ffn_gemm<2048, 512, 64, false><<<dim3(80, 8), 256, 0, stream>>>(hbuf, Wt, b2, ybuf, offs, tileoff);
  combine_kernel<<<T_, 64, 0, stream>>>(ybuf, tok2row, out);
}